// Round 1
// baseline (2933.003 us; speedup 1.0000x reference)
//
#include <hip/hip_runtime.h>
#include <hip/hip_bf16.h>

// Problem constants (fixed by setup_inputs): N = 256*64*64 rows, C = 64.
#define NROWS   1048576
#define CDIM    64
#define SBLK    4096          // spatial positions per block (64*64)

__device__ __forceinline__ float bf2f(unsigned short u) {
    unsigned w = ((unsigned)u) << 16;
    return __builtin_bit_cast(float, w);
}
__device__ __forceinline__ unsigned short f2bf(float f) {
    unsigned u = __builtin_bit_cast(unsigned, f);
    u += 0x7fffu + ((u >> 16) & 1u);   // RNE
    return (unsigned short)(u >> 16);
}

// ---------------------------------------------------------------------------
// K0: transpose small weight matrices once so every GEMV inner loop reads
// CONSECUTIVE weights -> compiler emits merged s_load_dwordx16 (uniform addr).
//   w11T[c*64+o] = w11[o*64+c]   (layer-1 weights, used c-outer)
//   w21T likewise
//   uW1T[o*128+c] = uW1[c*64+o]  (used o-outer)
//   uW2T[o*64+c]  = uW2[c*64+o]
// ---------------------------------------------------------------------------
__global__ void k_prep(const float* __restrict__ w11, const float* __restrict__ w21,
                       const float* __restrict__ uW1, const float* __restrict__ uW2,
                       float* __restrict__ w11T, float* __restrict__ w21T,
                       float* __restrict__ uW1T, float* __restrict__ uW2T)
{
    int t = threadIdx.x;
    for (int i = t; i < 4096; i += 256) {
        int o = i >> 6, c = i & 63;       // i = o*64 + c
        w11T[c * 64 + o] = w11[i];
        w21T[c * 64 + o] = w21[i];
    }
    for (int i = t; i < 8192; i += 256) { // i = c*64 + o  (uW1 is (128,64))
        int c = i >> 6, o = i & 63;
        uW1T[o * 128 + c] = uW1[i];
    }
    for (int i = t; i < 4096; i += 256) { // i = c*64 + o
        int c = i >> 6, o = i & 63;
        uW2T[o * 64 + c] = uW2[i];
    }
}

// ---------------------------------------------------------------------------
// K1: both 2-layer MLP branches.  Row-per-thread GEMV.
//  - x tile staged to LDS as bf16 (pad 66 -> 2-way bank alias = free)
//  - layer1: c-outer, accumulators z[64] in VGPRs, weights w11T[c*64+o]
//    consecutive -> scalar loads
//  - layer2: c-outer reading t1 from per-thread LDS row, weights w12[o*64+c]
//    read with wrow = w12T?  layer2 keeps ORIGINAL w12 (o,c): we use c-outer
//    with stride-64 scalar loads?  No: c-outer needs w[.,c] over o; instead we
//    use w12 as-is with o-outer is impossible (t1 dynamic).  So layer2 is also
//    c-outer and needs w12 transposed-by-c: but w12[o*64+c] over o is stride
//    64.  Trick: w12's role in  m1[o] = sum_c t1[c]*w12[o][c]  with c-outer
//    needs column c of w12 (stride 64).  We accept stride-64 s_load_dword here
//    (64 scalar loads vs 128 VALU cycles per iter -> hidden by scalar pipe).
// Outputs M1/M2 in (b, outch, s) layout, coalesced stores (lanes = s).
// ---------------------------------------------------------------------------
__global__ __launch_bounds__(256) void k_mlp(
    const float* __restrict__ x,
    const float* __restrict__ w11T, const float* __restrict__ b11,
    const float* __restrict__ w12,  const float* __restrict__ b12,
    const float* __restrict__ w21T, const float* __restrict__ b21,
    const float* __restrict__ w22,  const float* __restrict__ b22,
    unsigned short* __restrict__ M1, unsigned short* __restrict__ M2)
{
    __shared__ unsigned short xs[256 * 66];
    __shared__ unsigned short ts[256 * 66];
    const int t  = threadIdx.x;
    const int n0 = blockIdx.x * 256;
    const int n  = n0 + t;
    const int b  = n >> 12, s = n & (SBLK - 1);

    // stage x tile (256 rows x 64 ch), coalesced float4 loads
    {
        const float4* X4 = reinterpret_cast<const float4*>(x) + (size_t)n0 * 16;
        for (int i = t; i < 4096; i += 256) {
            float4 v = X4[i];
            int r = i >> 4, c0 = (i & 15) * 4;
            int base = r * 66 + c0;
            xs[base + 0] = f2bf(v.x); xs[base + 1] = f2bf(v.y);
            xs[base + 2] = f2bf(v.z); xs[base + 3] = f2bf(v.w);
        }
    }
    __syncthreads();

    float z[64];

    for (int branch = 0; branch < 2; ++branch) {
        const float* wAT = branch == 0 ? w11T : w21T;
        const float* bA  = branch == 0 ? b11  : b21;
        const float* wB  = branch == 0 ? w12  : w22;
        const float* bB  = branch == 0 ? b12  : b22;
        unsigned short* Mo = branch == 0 ? M1 : M2;

        // layer 1: t1[o] = relu(b + sum_c x[c] * W1[o][c]); W1T[c*64+o] consecutive
        #pragma unroll
        for (int o = 0; o < 64; ++o) z[o] = bA[o];
        for (int c = 0; c < 64; ++c) {
            float v = bf2f(xs[t * 66 + c]);
            const float* wp = wAT + c * 64;
            #pragma unroll
            for (int o = 0; o < 64; ++o) z[o] = fmaf(v, wp[o], z[o]);
        }
        // park relu(t1) in this thread's private LDS row (same-thread RAW, no barrier)
        #pragma unroll
        for (int o = 0; o < 64; ++o) ts[t * 66 + o] = f2bf(fmaxf(z[o], 0.f));

        // layer 2: m[o] = relu(b + sum_c t1[c] * W2[o][c]); stride-64 scalar loads
        #pragma unroll
        for (int o = 0; o < 64; ++o) z[o] = bB[o];
        for (int c = 0; c < 64; ++c) {
            float v = bf2f(ts[t * 66 + c]);
            const float* wp = wB + c;        // wp[o*64] uniform scalar loads
            #pragma unroll
            for (int o = 0; o < 64; ++o) z[o] = fmaf(v, wp[o * 64], z[o]);
        }
        // store (b, o, s): lanes = consecutive s -> coalesced 128B per o
        unsigned short* mp = Mo + ((size_t)b << 18) + s;
        #pragma unroll
        for (int o = 0; o < 64; ++o)
            mp[(size_t)o << 12] = f2bf(fmaxf(z[o], 0.f));
    }
}

// ---------------------------------------------------------------------------
// K2: corr[b,c] = A(64x64) @ B(64x64);  h = sqrt(relu(corr)) written IN-PLACE
// over M1[b][c] (that slice is read only by this workgroup, fully consumed
// into LDS before the barrier).
// ---------------------------------------------------------------------------
__global__ __launch_bounds__(256) void k_corr(
    unsigned short* __restrict__ M1, const unsigned short* __restrict__ M2)
{
    __shared__ float As[64 * 68];   // As[k*68 + i] = A[i][k] (transposed)
    __shared__ float Bs[64 * 68];   // Bs[k*68 + j] = B[k][j]
    const int t = threadIdx.x;
    const size_t base = (size_t)blockIdx.x << 12;   // (b*64+c)*4096
    const uint4* A4 = reinterpret_cast<const uint4*>(M1 + base);
    const uint4* B4 = reinterpret_cast<const uint4*>(M2 + base);

    #pragma unroll
    for (int l = 0; l < 2; ++l) {
        int f8 = t + l * 256;            // uint4 index (8 bf16 each), 512 total
        uint4 pa = A4[f8];
        uint4 pb = B4[f8];
        int f = f8 * 8;
        int row = f >> 6;                // i for A, k for B
        int col0 = f & 63;               // k0 for A, j0 for B (multiple of 8)
        unsigned pav[4] = { pa.x, pa.y, pa.z, pa.w };
        unsigned pbv[4] = { pb.x, pb.y, pb.z, pb.w };
        #pragma unroll
        for (int m = 0; m < 4; ++m) {
            As[(col0 + 2 * m + 0) * 68 + row] = bf2f((unsigned short)(pav[m] & 0xffff));
            As[(col0 + 2 * m + 1) * 68 + row] = bf2f((unsigned short)(pav[m] >> 16));
            Bs[row * 68 + col0 + 2 * m + 0]   = bf2f((unsigned short)(pbv[m] & 0xffff));
            Bs[row * 68 + col0 + 2 * m + 1]   = bf2f((unsigned short)(pbv[m] >> 16));
        }
    }
    __syncthreads();

    const int tj = t & 15, ti = t >> 4;  // 16x16 thread grid, 4x4 tile each
    float acc[4][4];
    #pragma unroll
    for (int r = 0; r < 4; ++r)
        #pragma unroll
        for (int c = 0; c < 4; ++c) acc[r][c] = 0.f;

    for (int k = 0; k < 64; ++k) {
        float4 a = *reinterpret_cast<const float4*>(&As[k * 68 + 4 * ti]);
        float4 bv = *reinterpret_cast<const float4*>(&Bs[k * 68 + 4 * tj]);
        float av[4] = { a.x, a.y, a.z, a.w };
        float bb[4] = { bv.x, bv.y, bv.z, bv.w };
        #pragma unroll
        for (int r = 0; r < 4; ++r)
            #pragma unroll
            for (int c = 0; c < 4; ++c)
                acc[r][c] = fmaf(av[r], bb[c], acc[r][c]);
    }

    unsigned short* Hp = M1 + base;      // overwrite A slice with h
    #pragma unroll
    for (int r = 0; r < 4; ++r) {
        ushort4 hv;
        hv.x = f2bf(sqrtf(fmaxf(acc[r][0], 0.f)));
        hv.y = f2bf(sqrtf(fmaxf(acc[r][1], 0.f)));
        hv.z = f2bf(sqrtf(fmaxf(acc[r][2], 0.f)));
        hv.w = f2bf(sqrtf(fmaxf(acc[r][3], 0.f)));
        *reinterpret_cast<ushort4*>(&Hp[(4 * ti + r) * 64 + 4 * tj]) = hv;
    }
}

// ---------------------------------------------------------------------------
// K3: z1 = [x, h] @ uW1 + ub1  (o-outer GEMV; x burst in regs, h gathered
// per-channel coalesced from (b,c,s) layout; uW1T rows consecutive -> x16
// scalar loads).  z1 stored bf16 row-major.
// ---------------------------------------------------------------------------
__global__ __launch_bounds__(256) void k_fc1(
    const float* __restrict__ x, const unsigned short* __restrict__ H,
    const float* __restrict__ uW1T, const float* __restrict__ ub1,
    unsigned short* __restrict__ Z1)
{
    const int n = blockIdx.x * 256 + threadIdx.x;
    const int b = n >> 12, s = n & (SBLK - 1);

    float xr[64];
    const float4* X4 = reinterpret_cast<const float4*>(x) + (size_t)n * 16;
    #pragma unroll
    for (int i = 0; i < 16; ++i) {
        float4 v = X4[i];
        xr[4 * i] = v.x; xr[4 * i + 1] = v.y; xr[4 * i + 2] = v.z; xr[4 * i + 3] = v.w;
    }
    float hr[64];
    const unsigned short* Hp = H + ((size_t)b << 18) + s;
    #pragma unroll
    for (int c = 0; c < 64; ++c) hr[c] = bf2f(Hp[(size_t)c << 12]);

    unsigned short* zp = Z1 + (size_t)n * 64;
    for (int o = 0; o < 64; ++o) {
        const float* wp = uW1T + o * 128;     // 128 consecutive floats
        float acc = ub1[o];
        #pragma unroll
        for (int c = 0; c < 64; ++c) acc = fmaf(xr[c], wp[c], acc);
        #pragma unroll
        for (int c = 0; c < 64; ++c) acc = fmaf(hr[c], wp[64 + c], acc);
        zp[o] = f2bf(acc);
    }
}

// ---------------------------------------------------------------------------
// K4/K6: per-channel sum & sumsq of a bf16 (N x 64) array -> atomics.
// ---------------------------------------------------------------------------
__global__ __launch_bounds__(256) void k_stats(
    const unsigned short* __restrict__ Z, float* __restrict__ sum, float* __restrict__ sq)
{
    __shared__ float ls[4][64], lq[4][64];
    const int q = threadIdx.x >> 6, c = threadIdx.x & 63;
    const size_t r0 = (size_t)blockIdx.x * 1024;
    float s = 0.f, ss = 0.f;
    for (int r = q; r < 1024; r += 4) {
        float v = bf2f(Z[(r0 + r) * 64 + c]);
        s += v; ss += v * v;
    }
    ls[q][c] = s; lq[q][c] = ss;
    __syncthreads();
    if (threadIdx.x < 64) {
        float S = ls[0][c] + ls[1][c] + ls[2][c] + ls[3][c];
        float Q = lq[0][c] + lq[1][c] + lq[2][c] + lq[3][c];
        atomicAdd(&sum[c], S);
        atomicAdd(&sq[c], Q);
    }
}

__global__ void k_final(const float* __restrict__ sum, const float* __restrict__ sq,
                        const float* __restrict__ g, const float* __restrict__ be,
                        float* __restrict__ scale, float* __restrict__ shift)
{
    int c = threadIdx.x;
    if (c < 64) {
        const float invN = 1.f / (float)NROWS;
        float mu  = sum[c] * invN;
        float var = sq[c] * invN - mu * mu;
        float rs  = rsqrtf(var + 1e-5f);
        float sc  = g[c] * rs;
        scale[c] = sc;
        shift[c] = be[c] - mu * sc;
    }
}

// ---------------------------------------------------------------------------
// K5: y = relu(z1*scale1+shift1);  z2 = y @ uW2 + ub2  (o-outer GEMV).
// ---------------------------------------------------------------------------
__global__ __launch_bounds__(256) void k_fc2(
    const unsigned short* __restrict__ Z1,
    const float* __restrict__ uW2T, const float* __restrict__ ub2,
    const float* __restrict__ scale1, const float* __restrict__ shift1,
    unsigned short* __restrict__ Z2)
{
    const int n = blockIdx.x * 256 + threadIdx.x;
    float y[64];
    const uint4* zr4 = reinterpret_cast<const uint4*>(Z1 + (size_t)n * 64);
    #pragma unroll
    for (int i = 0; i < 8; ++i) {
        uint4 p = zr4[i];
        unsigned pv[4] = { p.x, p.y, p.z, p.w };
        #pragma unroll
        for (int j = 0; j < 4; ++j) {
            int c = i * 8 + j * 2;
            float lo = bf2f((unsigned short)(pv[j] & 0xffff));
            float hi = bf2f((unsigned short)(pv[j] >> 16));
            y[c]     = fmaxf(fmaf(lo, scale1[c],     shift1[c]),     0.f);
            y[c + 1] = fmaxf(fmaf(hi, scale1[c + 1], shift1[c + 1]), 0.f);
        }
    }
    unsigned short* zp = Z2 + (size_t)n * 64;
    for (int o = 0; o < 64; ++o) {
        const float* wp = uW2T + o * 64;     // consecutive
        float acc = ub2[o];
        #pragma unroll
        for (int c = 0; c < 64; ++c) acc = fmaf(y[c], wp[c], acc);
        zp[o] = f2bf(acc);
    }
}

// ---------------------------------------------------------------------------
// K7: out = relu(z2*scale2+shift2) + x   (float4 elementwise)
// ---------------------------------------------------------------------------
__global__ __launch_bounds__(256) void k_out(
    const float* __restrict__ x, const unsigned short* __restrict__ Z2,
    const float* __restrict__ scale2, const float* __restrict__ shift2,
    float* __restrict__ out)
{
    const int i  = blockIdx.x * 256 + threadIdx.x;   // float4 index
    const int c0 = (i & 15) * 4;
    float4 xv = reinterpret_cast<const float4*>(x)[i];
    ushort4 zv = reinterpret_cast<const ushort4*>(Z2)[i];
    float4 o;
    o.x = fmaxf(fmaf(bf2f(zv.x), scale2[c0 + 0], shift2[c0 + 0]), 0.f) + xv.x;
    o.y = fmaxf(fmaf(bf2f(zv.y), scale2[c0 + 1], shift2[c0 + 1]), 0.f) + xv.y;
    o.z = fmaxf(fmaf(bf2f(zv.z), scale2[c0 + 2], shift2[c0 + 2]), 0.f) + xv.z;
    o.w = fmaxf(fmaf(bf2f(zv.w), scale2[c0 + 3], shift2[c0 + 3]), 0.f) + xv.w;
    reinterpret_cast<float4*>(out)[i] = o;
}

// ---------------------------------------------------------------------------
extern "C" void kernel_launch(void* const* d_in, const int* in_sizes, int n_in,
                              void* d_out, int out_size, void* d_ws, size_t ws_size,
                              hipStream_t stream)
{
    const float* x   = (const float*)d_in[0];
    const float* w11 = (const float*)d_in[1];
    const float* b11 = (const float*)d_in[2];
    const float* w12 = (const float*)d_in[3];
    const float* b12 = (const float*)d_in[4];
    const float* w21 = (const float*)d_in[5];
    const float* b21 = (const float*)d_in[6];
    const float* w22 = (const float*)d_in[7];
    const float* b22 = (const float*)d_in[8];
    const float* uW1 = (const float*)d_in[9];
    const float* ub1 = (const float*)d_in[10];
    const float* g1  = (const float*)d_in[11];
    const float* be1 = (const float*)d_in[12];
    const float* uW2 = (const float*)d_in[13];
    const float* ub2 = (const float*)d_in[14];
    const float* g2  = (const float*)d_in[15];
    const float* be2 = (const float*)d_in[16];

    char* ws = (char*)d_ws;
    const size_t BUF = (size_t)NROWS * 64 * sizeof(unsigned short);  // 128 MiB
    unsigned short* B0 = (unsigned short*)ws;              // M1 -> H -> Z2
    unsigned short* B1 = (unsigned short*)(ws + BUF);      // M2 -> Z1
    float* stats  = (float*)(ws + 2 * BUF);                // 512 floats
    float* sum1   = stats;        float* sq1    = stats + 64;
    float* sum2   = stats + 128;  float* sq2    = stats + 192;
    float* scale1 = stats + 256;  float* shift1 = stats + 320;
    float* scale2 = stats + 384;  float* shift2 = stats + 448;
    float* wT     = (float*)(ws + 2 * BUF + 2048);         // transposed weights
    float* w11T = wT;            // 4096
    float* w21T = wT + 4096;     // 4096
    float* uW2T = wT + 8192;     // 4096
    float* uW1T = wT + 12288;    // 8192

    hipMemsetAsync(stats, 0, 256 * sizeof(float), stream);

    k_prep<<<1, 256, 0, stream>>>(w11, w21, uW1, uW2, w11T, w21T, uW1T, uW2T);
    k_mlp<<<NROWS / 256, 256, 0, stream>>>(x, w11T, b11, w12, b12, w21T, b21, w22, b22, B0, B1);
    k_corr<<<16384, 256, 0, stream>>>(B0, B1);
    k_fc1<<<NROWS / 256, 256, 0, stream>>>(x, B0, uW1T, ub1, B1);
    k_stats<<<1024, 256, 0, stream>>>(B1, sum1, sq1);
    k_final<<<1, 64, 0, stream>>>(sum1, sq1, g1, be1, scale1, shift1);
    k_fc2<<<NROWS / 256, 256, 0, stream>>>(B1, uW2T, ub2, scale1, shift1, B0);
    k_stats<<<1024, 256, 0, stream>>>(B0, sum2, sq2);
    k_final<<<1, 64, 0, stream>>>(sum2, sq2, g2, be2, scale2, shift2);
    k_out<<<NROWS * 64 / 4 / 256, 256, 0, stream>>>(x, B0, scale2, shift2, (float*)d_out);
}

// Round 2
// 1019.865 us; speedup vs baseline: 2.8759x; 2.8759x over previous
//
#include <hip/hip_runtime.h>

// Problem constants (fixed by setup_inputs): N = 256*64*64 rows, C = 64.
#define NROWS   1048576
#define SBLK    4096          // spatial positions per block (64*64)

using bfrag = __attribute__((ext_vector_type(8))) short;   // 8 bf16 (4 VGPRs)
using ffrag = __attribute__((ext_vector_type(4))) float;   // 4 fp32 acc

__device__ __forceinline__ float bf2f(unsigned short u) {
    unsigned w = ((unsigned)u) << 16;
    return __builtin_bit_cast(float, w);
}
__device__ __forceinline__ unsigned short f2bf(float f) {
    unsigned u = __builtin_bit_cast(unsigned, f);
    u += 0x7fffu + ((u >> 16) & 1u);   // RNE
    return (unsigned short)(u >> 16);
}
__device__ __forceinline__ short pk(float f) { return (short)f2bf(f); }

// ---------------------------------------------------------------------------
// K0: cast weights to bf16 in B^T[n][k] fragment-friendly layout.
//  layer convs: W given (o,c), need BT[o][c] -> as-is, just cast.
//  uW1 given (c=0..127, o): uW1bt[o*128+c] = uW1[c*64+o]
//  uW2 given (c, o):        uW2bt[o*64+c]  = uW2[c*64+o]
// ---------------------------------------------------------------------------
__global__ void k_prep(const float* __restrict__ w11, const float* __restrict__ w12,
                       const float* __restrict__ w21, const float* __restrict__ w22,
                       const float* __restrict__ uW1, const float* __restrict__ uW2,
                       unsigned short* __restrict__ w11b, unsigned short* __restrict__ w12b,
                       unsigned short* __restrict__ w21b, unsigned short* __restrict__ w22b,
                       unsigned short* __restrict__ uW1bt, unsigned short* __restrict__ uW2bt)
{
    int t = threadIdx.x;
    for (int i = t; i < 4096; i += 256) {
        w11b[i] = f2bf(w11[i]);
        w12b[i] = f2bf(w12[i]);
        w21b[i] = f2bf(w21[i]);
        w22b[i] = f2bf(w22[i]);
        int o = i >> 6, c = i & 63;
        uW2bt[o * 64 + c] = f2bf(uW2[c * 64 + o]);
    }
    for (int i = t; i < 8192; i += 256) {
        int o = i >> 7, c = i & 127;
        uW1bt[o * 128 + c] = f2bf(uW1[c * 64 + o]);
    }
}

// ---------------------------------------------------------------------------
// K1: both 2-layer MLP branches via MFMA. WG=256 (4 waves), 64 rows/iter.
// A-frag: lane = A[m=lane&15][k=quad*8+j].  B-frag from BT[n][k] (8 consec k).
// C/D: col=lane&15, row=quad*4+reg.
// Layer1->Layer2 handoff through LDS ts (same-wave rows -> no barrier).
// Output M1/M2 in (b, o, s) layout via LDS transpose -> 128B coalesced stores.
// ---------------------------------------------------------------------------
__global__ __launch_bounds__(256) void k_mlp(
    const float* __restrict__ x,
    const unsigned short* __restrict__ w11b, const float* __restrict__ b11,
    const unsigned short* __restrict__ w12b, const float* __restrict__ b12,
    const unsigned short* __restrict__ w21b, const float* __restrict__ b21,
    const unsigned short* __restrict__ w22b, const float* __restrict__ b22,
    unsigned short* __restrict__ M1, unsigned short* __restrict__ M2)
{
    __shared__ unsigned short xs[64 * 72];   // pad 72: frag reads 16B-aligned, 2-way free
    __shared__ unsigned short ts[64 * 72];
    __shared__ unsigned short t2[64 * 67];   // pad 67 (odd-ish): transposed b16 reads
    const int t   = threadIdx.x;
    const int w   = t >> 6, ln = t & 63;
    const int col = ln & 15, q = ln >> 4;

    for (int blk = blockIdx.x; blk < NROWS / 64; blk += gridDim.x) {
        const int n0 = blk * 64;
        const int b = n0 >> 12, s0 = n0 & (SBLK - 1);

        // stage x tile -> LDS bf16 (coalesced float4 reads, uint2 LDS writes)
        const float4* X4 = reinterpret_cast<const float4*>(x) + (size_t)n0 * 16;
        #pragma unroll
        for (int j = 0; j < 4; ++j) {
            int i = t + j * 256;
            float4 v = X4[i];
            int row = i >> 4, c0 = (i & 15) * 4;
            unsigned lo = ((unsigned)f2bf(v.x)) | ((unsigned)f2bf(v.y) << 16);
            unsigned hi = ((unsigned)f2bf(v.z)) | ((unsigned)f2bf(v.w) << 16);
            *reinterpret_cast<uint2*>(&xs[row * 72 + c0]) = make_uint2(lo, hi);
        }
        __syncthreads();

        #pragma unroll
        for (int br = 0; br < 2; ++br) {
            const unsigned short* wA = br ? w21b : w11b;
            const unsigned short* wB = br ? w22b : w12b;
            const float* bA = br ? b21 : b11;
            const float* bB = br ? b22 : b12;
            unsigned short* M = br ? M2 : M1;

            // ---- layer 1 ----
            bfrag bw[2][4];
            #pragma unroll
            for (int kt = 0; kt < 2; ++kt)
                #pragma unroll
                for (int ct = 0; ct < 4; ++ct)
                    bw[kt][ct] = *reinterpret_cast<const bfrag*>(
                        wA + (ct * 16 + col) * 64 + kt * 32 + q * 8);
            bfrag a0 = *reinterpret_cast<const bfrag*>(&xs[(w * 16 + col) * 72 + q * 8]);
            bfrag a1 = *reinterpret_cast<const bfrag*>(&xs[(w * 16 + col) * 72 + 32 + q * 8]);
            #pragma unroll
            for (int ct = 0; ct < 4; ++ct) {
                ffrag acc = {0.f, 0.f, 0.f, 0.f};
                acc = __builtin_amdgcn_mfma_f32_16x16x32_bf16(a0, bw[0][ct], acc, 0, 0, 0);
                acc = __builtin_amdgcn_mfma_f32_16x16x32_bf16(a1, bw[1][ct], acc, 0, 0, 0);
                float bias = bA[ct * 16 + col];
                #pragma unroll
                for (int r = 0; r < 4; ++r) {
                    float v = fmaxf(acc[r] + bias, 0.f);
                    ts[(w * 16 + q * 4 + r) * 72 + ct * 16 + col] = f2bf(v);
                }
            }
            // ---- layer 2 (same-wave rows of ts; compiler inserts lgkm waits) ----
            #pragma unroll
            for (int kt = 0; kt < 2; ++kt)
                #pragma unroll
                for (int ct = 0; ct < 4; ++ct)
                    bw[kt][ct] = *reinterpret_cast<const bfrag*>(
                        wB + (ct * 16 + col) * 64 + kt * 32 + q * 8);
            a0 = *reinterpret_cast<const bfrag*>(&ts[(w * 16 + col) * 72 + q * 8]);
            a1 = *reinterpret_cast<const bfrag*>(&ts[(w * 16 + col) * 72 + 32 + q * 8]);
            #pragma unroll
            for (int ct = 0; ct < 4; ++ct) {
                ffrag acc = {0.f, 0.f, 0.f, 0.f};
                acc = __builtin_amdgcn_mfma_f32_16x16x32_bf16(a0, bw[0][ct], acc, 0, 0, 0);
                acc = __builtin_amdgcn_mfma_f32_16x16x32_bf16(a1, bw[1][ct], acc, 0, 0, 0);
                float bias = bB[ct * 16 + col];
                #pragma unroll
                for (int r = 0; r < 4; ++r) {
                    float v = fmaxf(acc[r] + bias, 0.f);
                    t2[(w * 16 + q * 4 + r) * 67 + ct * 16 + col] = f2bf(v);
                }
            }
            __syncthreads();
            // transposed store: wave w covers o in [w*16, w*16+16), lanes = s
            unsigned short* Mp = M + ((size_t)b << 18) + s0 + ln;
            #pragma unroll
            for (int i = 0; i < 16; ++i) {
                int o = w * 16 + i;
                Mp[(size_t)o * SBLK] = t2[ln * 67 + o];
            }
            __syncthreads();
        }
    }
}

// ---------------------------------------------------------------------------
// K2: corr[b,c] = A(64x64) @ B(64x64);  h = sqrt(relu(corr)) IN-PLACE over M1.
// (unchanged from R1 — vector version, not the bottleneck yet)
// ---------------------------------------------------------------------------
__global__ __launch_bounds__(256) void k_corr(
    unsigned short* __restrict__ M1, const unsigned short* __restrict__ M2)
{
    __shared__ float As[64 * 68];   // As[k*68 + i] = A[i][k]
    __shared__ float Bs[64 * 68];   // Bs[k*68 + j] = B[k][j]
    const int t = threadIdx.x;
    const size_t base = (size_t)blockIdx.x << 12;
    const uint4* A4 = reinterpret_cast<const uint4*>(M1 + base);
    const uint4* B4 = reinterpret_cast<const uint4*>(M2 + base);

    #pragma unroll
    for (int l = 0; l < 2; ++l) {
        int f8 = t + l * 256;
        uint4 pa = A4[f8];
        uint4 pb = B4[f8];
        int f = f8 * 8;
        int row = f >> 6;
        int col0 = f & 63;
        unsigned pav[4] = { pa.x, pa.y, pa.z, pa.w };
        unsigned pbv[4] = { pb.x, pb.y, pb.z, pb.w };
        #pragma unroll
        for (int m = 0; m < 4; ++m) {
            As[(col0 + 2 * m + 0) * 68 + row] = bf2f((unsigned short)(pav[m] & 0xffff));
            As[(col0 + 2 * m + 1) * 68 + row] = bf2f((unsigned short)(pav[m] >> 16));
            Bs[row * 68 + col0 + 2 * m + 0]   = bf2f((unsigned short)(pbv[m] & 0xffff));
            Bs[row * 68 + col0 + 2 * m + 1]   = bf2f((unsigned short)(pbv[m] >> 16));
        }
    }
    __syncthreads();

    const int tj = t & 15, ti = t >> 4;
    float acc[4][4];
    #pragma unroll
    for (int r = 0; r < 4; ++r)
        #pragma unroll
        for (int c = 0; c < 4; ++c) acc[r][c] = 0.f;

    for (int k = 0; k < 64; ++k) {
        float4 a  = *reinterpret_cast<const float4*>(&As[k * 68 + 4 * ti]);
        float4 bv = *reinterpret_cast<const float4*>(&Bs[k * 68 + 4 * tj]);
        float av[4] = { a.x, a.y, a.z, a.w };
        float bb[4] = { bv.x, bv.y, bv.z, bv.w };
        #pragma unroll
        for (int r = 0; r < 4; ++r)
            #pragma unroll
            for (int c = 0; c < 4; ++c)
                acc[r][c] = fmaf(av[r], bb[c], acc[r][c]);
    }

    unsigned short* Hp = M1 + base;
    #pragma unroll
    for (int r = 0; r < 4; ++r) {
        ushort4 hv;
        hv.x = f2bf(sqrtf(fmaxf(acc[r][0], 0.f)));
        hv.y = f2bf(sqrtf(fmaxf(acc[r][1], 0.f)));
        hv.z = f2bf(sqrtf(fmaxf(acc[r][2], 0.f)));
        hv.w = f2bf(sqrtf(fmaxf(acc[r][3], 0.f)));
        *reinterpret_cast<ushort4*>(&Hp[(4 * ti + r) * 64 + 4 * tj]) = hv;
    }
}

// ---------------------------------------------------------------------------
// K3: z1 = [x, h] @ uW1 + ub1 via MFMA (K=128), BN1 stats fused.
// x-part A-frags straight from fp32 global; h-part via LDS transpose of H.
// ---------------------------------------------------------------------------
__global__ __launch_bounds__(256) void k_fc1(
    const float* __restrict__ x, const unsigned short* __restrict__ H,
    const unsigned short* __restrict__ uW1bt, const float* __restrict__ ub1,
    unsigned short* __restrict__ Z1, float* __restrict__ sum1, float* __restrict__ sq1)
{
    __shared__ unsigned short hs[64 * 72];
    __shared__ float redS[4][64], redQ[4][64];
    const int t   = threadIdx.x;
    const int w   = t >> 6, ln = t & 63;
    const int col = ln & 15, q = ln >> 4;

    // resident B-frags (16 x 4 VGPRs) + bias
    bfrag bw[4][4];
    #pragma unroll
    for (int kt = 0; kt < 4; ++kt)
        #pragma unroll
        for (int ct = 0; ct < 4; ++ct)
            bw[kt][ct] = *reinterpret_cast<const bfrag*>(
                uW1bt + (ct * 16 + col) * 128 + kt * 32 + q * 8);
    float bias[4];
    #pragma unroll
    for (int ct = 0; ct < 4; ++ct) bias[ct] = ub1[ct * 16 + col];

    float sA[4] = {0, 0, 0, 0}, qA[4] = {0, 0, 0, 0};

    for (int blk = blockIdx.x; blk < NROWS / 64; blk += gridDim.x) {
        const int n0 = blk * 64;
        const int b = n0 >> 12, s0 = n0 & (SBLK - 1);

        // stage H^T: thread (c = t&63, chunk = t>>6 of 16 s) -> hs[s][c]
        {
            const int c = t & 63, ch = t >> 6;
            const unsigned short* hp = H + ((size_t)b << 18) + (size_t)c * SBLK + s0 + ch * 16;
            uint4 p0 = reinterpret_cast<const uint4*>(hp)[0];
            uint4 p1 = reinterpret_cast<const uint4*>(hp)[1];
            unsigned pv[8] = { p0.x, p0.y, p0.z, p0.w, p1.x, p1.y, p1.z, p1.w };
            #pragma unroll
            for (int m = 0; m < 8; ++m) {
                int s = ch * 16 + m * 2;
                hs[(s + 0) * 72 + c] = (unsigned short)(pv[m] & 0xffff);
                hs[(s + 1) * 72 + c] = (unsigned short)(pv[m] >> 16);
            }
        }
        __syncthreads();

        const int row = w * 16 + col;
        bfrag ax[2];
        #pragma unroll
        for (int kt = 0; kt < 2; ++kt) {
            const float* xp = x + (size_t)(n0 + row) * 64 + kt * 32 + q * 8;
            float4 lo = reinterpret_cast<const float4*>(xp)[0];
            float4 hi = reinterpret_cast<const float4*>(xp)[1];
            bfrag a;
            a[0] = pk(lo.x); a[1] = pk(lo.y); a[2] = pk(lo.z); a[3] = pk(lo.w);
            a[4] = pk(hi.x); a[5] = pk(hi.y); a[6] = pk(hi.z); a[7] = pk(hi.w);
            ax[kt] = a;
        }
        bfrag ah0 = *reinterpret_cast<const bfrag*>(&hs[row * 72 + q * 8]);
        bfrag ah1 = *reinterpret_cast<const bfrag*>(&hs[row * 72 + 32 + q * 8]);

        #pragma unroll
        for (int ct = 0; ct < 4; ++ct) {
            ffrag acc = {0.f, 0.f, 0.f, 0.f};
            acc = __builtin_amdgcn_mfma_f32_16x16x32_bf16(ax[0], bw[0][ct], acc, 0, 0, 0);
            acc = __builtin_amdgcn_mfma_f32_16x16x32_bf16(ax[1], bw[1][ct], acc, 0, 0, 0);
            acc = __builtin_amdgcn_mfma_f32_16x16x32_bf16(ah0,  bw[2][ct], acc, 0, 0, 0);
            acc = __builtin_amdgcn_mfma_f32_16x16x32_bf16(ah1,  bw[3][ct], acc, 0, 0, 0);
            #pragma unroll
            for (int r = 0; r < 4; ++r) {
                float v = acc[r] + bias[ct];
                Z1[(size_t)(n0 + w * 16 + q * 4 + r) * 64 + ct * 16 + col] = f2bf(v);
                sA[ct] += v; qA[ct] += v * v;
            }
        }
        __syncthreads();
    }

    // fused BN stats: quad-shfl reduce -> LDS -> one atomic per channel per WG
    #pragma unroll
    for (int ct = 0; ct < 4; ++ct) {
        float s = sA[ct], qq = qA[ct];
        s  += __shfl_xor(s, 16);  s  += __shfl_xor(s, 32);
        qq += __shfl_xor(qq, 16); qq += __shfl_xor(qq, 32);
        if (q == 0) { redS[w][ct * 16 + col] = s; redQ[w][ct * 16 + col] = qq; }
    }
    __syncthreads();
    if (t < 64) {
        float S = redS[0][t] + redS[1][t] + redS[2][t] + redS[3][t];
        float Q = redQ[0][t] + redQ[1][t] + redQ[2][t] + redQ[3][t];
        atomicAdd(&sum1[t], S);
        atomicAdd(&sq1[t], Q);
    }
}

__global__ void k_final(const float* __restrict__ sum, const float* __restrict__ sq,
                        const float* __restrict__ g, const float* __restrict__ be,
                        float* __restrict__ scale, float* __restrict__ shift)
{
    int c = threadIdx.x;
    if (c < 64) {
        const float invN = 1.f / (float)NROWS;
        float mu  = sum[c] * invN;
        float var = sq[c] * invN - mu * mu;
        float rs  = rsqrtf(var + 1e-5f);
        float sc  = g[c] * rs;
        scale[c] = sc;
        shift[c] = be[c] - mu * sc;
    }
}

// ---------------------------------------------------------------------------
// K5: y = relu(BN1(z1)); z2 = y @ uW2 + ub2 via MFMA, BN2 stats fused.
// Fully LDS-free main loop: A direct from global w/ BN applied in regs.
// ---------------------------------------------------------------------------
__global__ __launch_bounds__(256) void k_fc2(
    const unsigned short* __restrict__ Z1, const unsigned short* __restrict__ uW2bt,
    const float* __restrict__ ub2, const float* __restrict__ scale1,
    const float* __restrict__ shift1,
    unsigned short* __restrict__ Z2, float* __restrict__ sum2, float* __restrict__ sq2)
{
    __shared__ float redS[4][64], redQ[4][64];
    const int t   = threadIdx.x;
    const int w   = t >> 6, ln = t & 63;
    const int col = ln & 15, q = ln >> 4;

    bfrag bw[2][4];
    #pragma unroll
    for (int kt = 0; kt < 2; ++kt)
        #pragma unroll
        for (int ct = 0; ct < 4; ++ct)
            bw[kt][ct] = *reinterpret_cast<const bfrag*>(
                uW2bt + (ct * 16 + col) * 64 + kt * 32 + q * 8);
    float bias[4];
    #pragma unroll
    for (int ct = 0; ct < 4; ++ct) bias[ct] = ub2[ct * 16 + col];
    float sc[2][8], sh[2][8];
    #pragma unroll
    for (int kt = 0; kt < 2; ++kt)
        #pragma unroll
        for (int j = 0; j < 8; ++j) {
            int c = kt * 32 + q * 8 + j;
            sc[kt][j] = scale1[c];
            sh[kt][j] = shift1[c];
        }

    float sA[4] = {0, 0, 0, 0}, qA[4] = {0, 0, 0, 0};

    const int wg = blockIdx.x * 4 + w;
    const int stride = gridDim.x * 4;
    for (int tile = wg; tile < NROWS / 16; tile += stride) {
        const size_t rbase = (size_t)tile * 16;
        bfrag a[2];
        #pragma unroll
        for (int kt = 0; kt < 2; ++kt) {
            const unsigned short* zp = Z1 + (rbase + col) * 64 + kt * 32 + q * 8;
            uint4 p = *reinterpret_cast<const uint4*>(zp);
            unsigned pv[4] = { p.x, p.y, p.z, p.w };
            bfrag av;
            #pragma unroll
            for (int m = 0; m < 4; ++m) {
                float lo = bf2f((unsigned short)(pv[m] & 0xffff));
                float hi = bf2f((unsigned short)(pv[m] >> 16));
                lo = fmaxf(fmaf(lo, sc[kt][2 * m],     sh[kt][2 * m]),     0.f);
                hi = fmaxf(fmaf(hi, sc[kt][2 * m + 1], sh[kt][2 * m + 1]), 0.f);
                av[2 * m] = pk(lo); av[2 * m + 1] = pk(hi);
            }
            a[kt] = av;
        }
        #pragma unroll
        for (int ct = 0; ct < 4; ++ct) {
            ffrag acc = {0.f, 0.f, 0.f, 0.f};
            acc = __builtin_amdgcn_mfma_f32_16x16x32_bf16(a[0], bw[0][ct], acc, 0, 0, 0);
            acc = __builtin_amdgcn_mfma_f32_16x16x32_bf16(a[1], bw[1][ct], acc, 0, 0, 0);
            #pragma unroll
            for (int r = 0; r < 4; ++r) {
                float v = acc[r] + bias[ct];
                Z2[(rbase + q * 4 + r) * 64 + ct * 16 + col] = f2bf(v);
                sA[ct] += v; qA[ct] += v * v;
            }
        }
    }

    #pragma unroll
    for (int ct = 0; ct < 4; ++ct) {
        float s = sA[ct], qq = qA[ct];
        s  += __shfl_xor(s, 16);  s  += __shfl_xor(s, 32);
        qq += __shfl_xor(qq, 16); qq += __shfl_xor(qq, 32);
        if (q == 0) { redS[w][ct * 16 + col] = s; redQ[w][ct * 16 + col] = qq; }
    }
    __syncthreads();
    if (t < 64) {
        float S = redS[0][t] + redS[1][t] + redS[2][t] + redS[3][t];
        float Q = redQ[0][t] + redQ[1][t] + redQ[2][t] + redQ[3][t];
        atomicAdd(&sum2[t], S);
        atomicAdd(&sq2[t], Q);
    }
}

// ---------------------------------------------------------------------------
// K7: out = relu(z2*scale2+shift2) + x   (float4 elementwise)
// ---------------------------------------------------------------------------
__global__ __launch_bounds__(256) void k_out(
    const float* __restrict__ x, const unsigned short* __restrict__ Z2,
    const float* __restrict__ scale2, const float* __restrict__ shift2,
    float* __restrict__ out)
{
    const int i  = blockIdx.x * 256 + threadIdx.x;
    const int c0 = (i & 15) * 4;
    float4 xv = reinterpret_cast<const float4*>(x)[i];
    ushort4 zv = reinterpret_cast<const ushort4*>(Z2)[i];
    float4 o;
    o.x = fmaxf(fmaf(bf2f(zv.x), scale2[c0 + 0], shift2[c0 + 0]), 0.f) + xv.x;
    o.y = fmaxf(fmaf(bf2f(zv.y), scale2[c0 + 1], shift2[c0 + 1]), 0.f) + xv.y;
    o.z = fmaxf(fmaf(bf2f(zv.z), scale2[c0 + 2], shift2[c0 + 2]), 0.f) + xv.z;
    o.w = fmaxf(fmaf(bf2f(zv.w), scale2[c0 + 3], shift2[c0 + 3]), 0.f) + xv.w;
    reinterpret_cast<float4*>(out)[i] = o;
}

// ---------------------------------------------------------------------------
extern "C" void kernel_launch(void* const* d_in, const int* in_sizes, int n_in,
                              void* d_out, int out_size, void* d_ws, size_t ws_size,
                              hipStream_t stream)
{
    const float* x   = (const float*)d_in[0];
    const float* w11 = (const float*)d_in[1];
    const float* b11 = (const float*)d_in[2];
    const float* w12 = (const float*)d_in[3];
    const float* b12 = (const float*)d_in[4];
    const float* w21 = (const float*)d_in[5];
    const float* b21 = (const float*)d_in[6];
    const float* w22 = (const float*)d_in[7];
    const float* b22 = (const float*)d_in[8];
    const float* uW1 = (const float*)d_in[9];
    const float* ub1 = (const float*)d_in[10];
    const float* g1  = (const float*)d_in[11];
    const float* be1 = (const float*)d_in[12];
    const float* uW2 = (const float*)d_in[13];
    const float* ub2 = (const float*)d_in[14];
    const float* g2  = (const float*)d_in[15];
    const float* be2 = (const float*)d_in[16];

    char* ws = (char*)d_ws;
    const size_t BUF = (size_t)NROWS * 64 * sizeof(unsigned short);  // 128 MiB
    unsigned short* B0 = (unsigned short*)ws;              // M1 -> H -> Z2
    unsigned short* B1 = (unsigned short*)(ws + BUF);      // M2 -> Z1
    float* stats  = (float*)(ws + 2 * BUF);                // 512 floats
    float* sum1   = stats;        float* sq1    = stats + 64;
    float* sum2   = stats + 128;  float* sq2    = stats + 192;
    float* scale1 = stats + 256;  float* shift1 = stats + 320;
    float* scale2 = stats + 384;  float* shift2 = stats + 448;
    unsigned short* wb = (unsigned short*)(ws + 2 * BUF + 2048);
    unsigned short* w11b  = wb;           // 4096
    unsigned short* w12b  = wb + 4096;    // 4096
    unsigned short* w21b  = wb + 8192;    // 4096
    unsigned short* w22b  = wb + 12288;   // 4096
    unsigned short* uW1bt = wb + 16384;   // 8192
    unsigned short* uW2bt = wb + 24576;   // 4096

    hipMemsetAsync(stats, 0, 256 * sizeof(float), stream);

    k_prep<<<1, 256, 0, stream>>>(w11, w12, w21, w22, uW1, uW2,
                                  w11b, w12b, w21b, w22b, uW1bt, uW2bt);
    k_mlp<<<2048, 256, 0, stream>>>(x, w11b, b11, w12b, b12, w21b, b21, w22b, b22, B0, B1);
    k_corr<<<16384, 256, 0, stream>>>(B0, B1);
    k_fc1<<<2048, 256, 0, stream>>>(x, B0, uW1bt, ub1, B1, sum1, sq1);
    k_final<<<1, 64, 0, stream>>>(sum1, sq1, g1, be1, scale1, shift1);
    k_fc2<<<2048, 256, 0, stream>>>(B1, uW2bt, ub2, scale1, shift1, B0, sum2, sq2);
    k_final<<<1, 64, 0, stream>>>(sum2, sq2, g2, be2, scale2, shift2);
    k_out<<<NROWS * 64 / 4 / 256, 256, 0, stream>>>(x, B0, scale2, shift2, (float*)d_out);
}